// Round 2
// baseline (689.831 us; speedup 1.0000x reference)
//
#include <hip/hip_runtime.h>

// FlowNet2 Resample2d (bilinear warp), B=8 C=32 H=512 W=512, ALL FLOAT32
// (round-1 NaN proved the buffers are f32: reading f32 as bf16 produced NaN
// bit patterns; a genuine-bf16 world has no NaN path in this kernel).
//
// One thread owns 4 consecutive-w pixels: float4 flow load, float4 output
// store per channel. Per-pixel weights and border-clamped gather offsets are
// channel-invariant -> computed once, reused across the 32-channel loop.
// 524,288 threads total = full occupancy (256 CU x 2048 thr).

namespace {
constexpr int B = 8, C = 32, H = 512, W = 512;
constexpr int HW = H * W;                 // 2^18
constexpr int NPIX = B * H * W;           // 2,097,152
constexpr int PPT = 4;                    // pixels per thread
constexpr int NTHREADS = NPIX / PPT;      // 524,288
constexpr int BLOCK = 256;
constexpr int GRID = NTHREADS / BLOCK;    // 2048 (exact)
}

__global__ __launch_bounds__(BLOCK) void resample2d_kernel(
    const float* __restrict__ in1,   // [B,C,H,W]
    const float* __restrict__ flow,  // [B,2,H,W] ch0=dx ch1=dy
    float* __restrict__ out)         // [B,C,H,W]
{
    const int t = blockIdx.x * BLOCK + threadIdx.x;
    const int pix = t * PPT;
    const int w = pix & (W - 1);          // multiple of 4 -> 16B aligned
    const int h = (pix >> 9) & (H - 1);
    const int b = pix >> 18;

    const size_t flowBase = (size_t)(b * 2) * HW + h * W + w;
    const float4 dx4 = *reinterpret_cast<const float4*>(flow + flowBase);
    const float4 dy4 = *reinterpret_cast<const float4*>(flow + flowBase + HW);

    const float dxs[PPT] = {dx4.x, dx4.y, dx4.z, dx4.w};
    const float dys[PPT] = {dy4.x, dy4.y, dy4.z, dy4.w};

    float wt[PPT][4];
    int   of[PPT][4];

#pragma unroll
    for (int j = 0; j < PPT; ++j) {
        const float xf = (float)(w + j) + dxs[j];
        const float yf = (float)h + dys[j];
        const float x0 = floorf(xf);
        const float y0 = floorf(yf);
        // Weights from UNCLAMPED fractional coords (matches reference).
        const float alpha = xf - x0;
        const float beta  = yf - y0;
        const int x0i = (int)x0;
        const int y0i = (int)y0;
        const int xL = min(max(x0i,     0), W - 1);
        const int xR = min(max(x0i + 1, 0), W - 1);
        const int yT = min(max(y0i,     0), H - 1);
        const int yB = min(max(y0i + 1, 0), H - 1);
        wt[j][0] = (1.0f - alpha) * (1.0f - beta);
        wt[j][1] = alpha * (1.0f - beta);
        wt[j][2] = (1.0f - alpha) * beta;
        wt[j][3] = alpha * beta;
        of[j][0] = yT * W + xL;
        of[j][1] = yT * W + xR;
        of[j][2] = yB * W + xL;
        of[j][3] = yB * W + xR;
    }

    const float* __restrict__ inb  = in1 + (size_t)b * C * HW;
    float* __restrict__       outp = out + (size_t)b * C * HW + h * W + w;

#pragma unroll 2
    for (int c = 0; c < C; ++c) {
        const float* __restrict__ p = inb + (size_t)c * HW;
        float4 r;
        r.x = wt[0][0] * p[of[0][0]] + wt[0][1] * p[of[0][1]]
            + wt[0][2] * p[of[0][2]] + wt[0][3] * p[of[0][3]];
        r.y = wt[1][0] * p[of[1][0]] + wt[1][1] * p[of[1][1]]
            + wt[1][2] * p[of[1][2]] + wt[1][3] * p[of[1][3]];
        r.z = wt[2][0] * p[of[2][0]] + wt[2][1] * p[of[2][1]]
            + wt[2][2] * p[of[2][2]] + wt[2][3] * p[of[2][3]];
        r.w = wt[3][0] * p[of[3][0]] + wt[3][1] * p[of[3][1]]
            + wt[3][2] * p[of[3][2]] + wt[3][3] * p[of[3][3]];
        *reinterpret_cast<float4*>(outp + (size_t)c * HW) = r;
    }
}

extern "C" void kernel_launch(void* const* d_in, const int* in_sizes, int n_in,
                              void* d_out, int out_size, void* d_ws, size_t ws_size,
                              hipStream_t stream) {
    const float* in1  = (const float*)d_in[0];
    const float* flow = (const float*)d_in[1];
    float* out = (float*)d_out;
    resample2d_kernel<<<GRID, BLOCK, 0, stream>>>(in1, flow, out);
}